// Round 2
// baseline (332.171 us; speedup 1.0000x reference)
//
#include <hip/hip_runtime.h>
#include <cstdint>

// ============================================================================
// Dual-source attention for MI355X (gfx950).
// KEY ALGEBRAIC FACT: the sentence-stream term q2·k2 is constant across the
// softmax (key) axis for each (b,h) -> softmax shift invariance -> sen/W2 are
// dead inputs. Compute: QKV = tokens@W1 (bf16 MFMA GEMM), then flash attention
// out = softmax(SCALE*Q K^T - 10000*(1-mask)) @ V.
// ============================================================================

typedef __bf16 bf16x8 __attribute__((ext_vector_type(8)));
typedef __bf16 bf16x4 __attribute__((ext_vector_type(4)));
typedef float  f32x4  __attribute__((ext_vector_type(4)));

#define MFMA16(a, b, c) __builtin_amdgcn_mfma_f32_16x16x32_bf16(a, b, c, 0, 0, 0)

__device__ __forceinline__ void lds_fence() {
    // within-wave cross-lane LDS visibility (write -> read by other lanes)
    asm volatile("s_waitcnt lgkmcnt(0)" ::: "memory");
    __builtin_amdgcn_sched_barrier(0);
}

static constexpr float SCALE = 0.08838834764831845f;  // (2*64)^-0.5

// ---------------------------------------------------------------------------
// tokens f32 -> bf16  (8,388,608 elements; grid 8192 x 256, 4 elems/thread)
// ---------------------------------------------------------------------------
__global__ __launch_bounds__(256) void k_cvt_tok(const float* __restrict__ in,
                                                 __bf16* __restrict__ out) {
    int i = (blockIdx.x * 256 + threadIdx.x) * 4;
    float4 v = *(const float4*)&in[i];
    bf16x4 o = {(__bf16)v.x, (__bf16)v.y, (__bf16)v.z, (__bf16)v.w};
    *(bf16x4*)&out[i] = o;
}

// ---------------------------------------------------------------------------
// W1 [1024][3072] f32 -> W1T [3072][1024] bf16 (transpose so the GEMM can
// read B-fragments as contiguous ds_read_b128). 32x32 tiles via padded LDS.
// grid = 32 * 96 = 3072 blocks.
// ---------------------------------------------------------------------------
__global__ __launch_bounds__(256) void k_w1t(const float* __restrict__ W1,
                                             __bf16* __restrict__ W1T) {
    __shared__ float t[32][33];
    int bx = blockIdx.x % 96, by = blockIdx.x / 96;
    int r0 = by * 32, c0 = bx * 32;
    int tr = threadIdx.x >> 3, tc = (threadIdx.x & 7) * 4;
    float4 v = *(const float4*)&W1[(size_t)(r0 + tr) * 3072 + c0 + tc];
    t[tr][tc + 0] = v.x; t[tr][tc + 1] = v.y; t[tr][tc + 2] = v.z; t[tr][tc + 3] = v.w;
    __syncthreads();
    bf16x4 o = {(__bf16)t[tc + 0][tr], (__bf16)t[tc + 1][tr],
                (__bf16)t[tc + 2][tr], (__bf16)t[tc + 3][tr]};
    *(bf16x4*)&W1T[(size_t)(c0 + tr) * 1024 + r0 + tc] = o;
}

// ---------------------------------------------------------------------------
// mask int32 [4][2048] -> penalty f32 = -10000*(1-m).  grid 32 x 256.
// ---------------------------------------------------------------------------
__global__ __launch_bounds__(256) void k_mask(const int* __restrict__ m,
                                              float* __restrict__ pen) {
    int i = blockIdx.x * 256 + threadIdx.x;
    pen[i] = -10000.0f * (1.0f - (float)m[i]);
}

// ---------------------------------------------------------------------------
// GEMM: C[8192][3072] = A[8192][1024] @ B[1024][3072], A,B bf16, acc f32.
// B supplied pre-transposed (W1T[3072][1024]). 128x128 tile, BK=32, 4 waves,
// each wave a 64x64 subtile = 4x4 MFMA frags of 16x16x32.
// LDS rows padded 32->40 bf16 (80B) => 2-way bank aliasing only (free).
// Epilogue: col<1024 -> Q[bh][n][d]; <2048 -> K[bh][n][d]; else V^T[bh][d][n].
// ---------------------------------------------------------------------------
__global__ __launch_bounds__(256) void k_gemm_qkv(const __bf16* __restrict__ A,
                                                  const __bf16* __restrict__ BT,
                                                  __bf16* __restrict__ Q,
                                                  __bf16* __restrict__ K,
                                                  __bf16* __restrict__ VT) {
    __shared__ __bf16 Asm[128 * 40];
    __shared__ __bf16 Bsm[128 * 40];
    const int tid = threadIdx.x;
    const int tm = blockIdx.x / 24, tn = blockIdx.x % 24;
    const int m0 = tm * 128, n0 = tn * 128;
    const int l = tid & 63, wv = tid >> 6;
    const int l15 = l & 15, l4 = l >> 4;
    const int wr = wv >> 1, wc = wv & 1;

    f32x4 acc[4][4];
#pragma unroll
    for (int i = 0; i < 4; ++i)
#pragma unroll
        for (int j = 0; j < 4; ++j) acc[i][j] = (f32x4){0.f, 0.f, 0.f, 0.f};

    for (int kt = 0; kt < 32; ++kt) {
        const int k0 = kt * 32;
        __syncthreads();  // protect previous iteration's frag reads
#pragma unroll
        for (int i = 0; i < 2; ++i) {
            int c = tid * 2 + i;          // 512 chunks of 16B per 8KB tile
            int row = c >> 2, qq = c & 3; // 4 chunks per 64B row
            *(uint4*)((char*)Asm + row * 80 + qq * 16) =
                *(const uint4*)((const char*)A + ((size_t)(m0 + row) * 1024 + k0) * 2 + qq * 16);
            *(uint4*)((char*)Bsm + row * 80 + qq * 16) =
                *(const uint4*)((const char*)BT + ((size_t)(n0 + row) * 1024 + k0) * 2 + qq * 16);
        }
        __syncthreads();

        bf16x8 af[4], bb[4];
#pragma unroll
        for (int mi = 0; mi < 4; ++mi)
            af[mi] = *(const bf16x8*)((const char*)Asm + (wr * 64 + mi * 16 + l15) * 80 + l4 * 16);
#pragma unroll
        for (int ni = 0; ni < 4; ++ni)
            bb[ni] = *(const bf16x8*)((const char*)Bsm + (wc * 64 + ni * 16 + l15) * 80 + l4 * 16);
#pragma unroll
        for (int mi = 0; mi < 4; ++mi)
#pragma unroll
            for (int ni = 0; ni < 4; ++ni)
                acc[mi][ni] = MFMA16(af[mi], bb[ni], acc[mi][ni]);
    }

    // Epilogue. D-frag layout: row = (l>>4)*4 + r, col = l&15  [m89-verified].
#pragma unroll
    for (int mi = 0; mi < 4; ++mi) {
        const int rowb = m0 + wr * 64 + mi * 16 + l4 * 4;  // 4-aligned
        const int b = rowb >> 11, n = rowb & 2047;
#pragma unroll
        for (int ni = 0; ni < 4; ++ni) {
            const int col = n0 + wc * 64 + ni * 16 + l15;
            const int str = col >> 10, cc = col & 1023;
            const int h = cc >> 6, d = cc & 63;
            const int bh = b * 16 + h;
            if (str == 2) {
                // V stored transposed [bh][d][n]; the 4 regs are consecutive n
                bf16x4 pv = {(__bf16)acc[mi][ni][0], (__bf16)acc[mi][ni][1],
                             (__bf16)acc[mi][ni][2], (__bf16)acc[mi][ni][3]};
                *(bf16x4*)&VT[((size_t)bh * 64 + d) * 2048 + n] = pv;
            } else {
                __bf16* dst = (str == 0) ? Q : K;
#pragma unroll
                for (int r = 0; r < 4; ++r)
                    dst[((size_t)bh * 2048 + n + r) * 64 + d] = (__bf16)acc[mi][ni][r];
            }
        }
    }
}

// ---------------------------------------------------------------------------
// Flash attention. grid = 64 bh * 32 qtiles (bh-major for KV L2 reuse),
// 256 threads = 4 waves, wave owns 16 q-rows. 64-key KV tiles.
// Swapped QK^T: S^T = mfma(K, Q^T)  -> lane holds 4 scores for q-row (l&15),
// keys (l>>4)*4+r (+16*kb): softmax reduce = in-lane + shfl_xor(16,32).
// PV: O^T = mfma(V^T, P^T) with P^T staged per-wave in padded LDS.
// LDS rows padded 128B->144B => 2-way bank aliasing only.
// ---------------------------------------------------------------------------
__global__ __launch_bounds__(256) void k_attn(const __bf16* __restrict__ Q,
                                              const __bf16* __restrict__ K,
                                              const __bf16* __restrict__ VT,
                                              const float* __restrict__ pen,
                                              float* __restrict__ out) {
    __shared__ __bf16 Ksm[64 * 72];
    __shared__ __bf16 Vsm[64 * 72];
    __shared__ __bf16 Psm[4][16 * 72];
    __shared__ float pensm[2048];
    __shared__ float osm[4][16 * 65];

    const int tid = threadIdx.x;
    const int bh = blockIdx.x >> 5, qt = blockIdx.x & 31;
    const int b = bh >> 4, h = bh & 15;
    const int wv = tid >> 6, l = tid & 63, l15 = l & 15, l4 = l >> 4;

    // stage mask penalties for this batch (read after first __syncthreads)
#pragma unroll
    for (int i = 0; i < 2; ++i) {
        int idx = (i * 256 + tid) * 4;
        *(float4*)&pensm[idx] = *(const float4*)&pen[b * 2048 + idx];
    }

    // Q fragments held in registers for the whole kernel (B-operand of QK^T)
    const size_t qrow = (size_t)bh * 2048 + qt * 64 + wv * 16 + l15;
    const bf16x8 q0 = *(const bf16x8*)&Q[qrow * 64 + l4 * 8];
    const bf16x8 q1 = *(const bf16x8*)&Q[qrow * 64 + 32 + l4 * 8];

    float m_run = -1e30f, l_run = 0.f;
    f32x4 o[4];
#pragma unroll
    for (int i = 0; i < 4; ++i) o[i] = (f32x4){0.f, 0.f, 0.f, 0.f};

    const char* Kg = (const char*)K + (size_t)bh * 2048 * 128;  // [n][d] rows, tile contiguous
    const char* Vg = (const char*)VT + (size_t)bh * 64 * 4096;  // [d][n] rows, stride 4KB

    for (int t = 0; t < 32; ++t) {
        __syncthreads();  // previous tile's compute done before overwrite
#pragma unroll
        for (int i = 0; i < 2; ++i) {
            int c = tid * 2 + i;          // 512 x 16B chunks
            int row = c >> 3, qq = c & 7; // 8 chunks per 128B row
            *(uint4*)((char*)Ksm + row * 144 + qq * 16) =
                *(const uint4*)(Kg + (size_t)t * 8192 + c * 16);
            *(uint4*)((char*)Vsm + row * 144 + qq * 16) =
                *(const uint4*)(Vg + (size_t)row * 4096 + t * 128 + qq * 16);
        }
        __syncthreads();

        // ---- QK^T (swapped): A = K rows, B = Q^T ----
        float sc[4][4];
#pragma unroll
        for (int kb = 0; kb < 4; ++kb) {
            bf16x8 kf0 = *(const bf16x8*)((const char*)Ksm + (kb * 16 + l15) * 144 + l4 * 16);
            bf16x8 kf1 = *(const bf16x8*)((const char*)Ksm + (kb * 16 + l15) * 144 + 64 + l4 * 16);
            f32x4 s = (f32x4){0.f, 0.f, 0.f, 0.f};
            s = MFMA16(kf0, q0, s);
            s = MFMA16(kf1, q1, s);
#pragma unroll
            for (int r = 0; r < 4; ++r)
                sc[kb][r] = SCALE * s[r] + pensm[t * 64 + kb * 16 + l4 * 4 + r];
        }

        // ---- online softmax (rows = q = l&15) ----
        float mx = sc[0][0];
#pragma unroll
        for (int kb = 0; kb < 4; ++kb)
#pragma unroll
            for (int r = 0; r < 4; ++r) mx = fmaxf(mx, sc[kb][r]);
        mx = fmaxf(mx, __shfl_xor(mx, 16, 64));
        mx = fmaxf(mx, __shfl_xor(mx, 32, 64));
        const float m_new = fmaxf(m_run, mx);
        const float alpha = __expf(m_run - m_new);
        float ps = 0.f;
        bf16x4 pk[4];
#pragma unroll
        for (int kb = 0; kb < 4; ++kb)
#pragma unroll
            for (int r = 0; r < 4; ++r) {
                float p = __expf(sc[kb][r] - m_new);
                ps += p;
                pk[kb][r] = (__bf16)p;
            }
        ps += __shfl_xor(ps, 16, 64);
        ps += __shfl_xor(ps, 32, 64);
        l_run = l_run * alpha + ps;
        m_run = m_new;
#pragma unroll
        for (int db = 0; db < 4; ++db) o[db] *= alpha;

        // ---- stage P^T (per-wave buffer, cross-lane within wave) ----
#pragma unroll
        for (int kb = 0; kb < 4; ++kb)
            *(bf16x4*)((char*)&Psm[wv][0] + l15 * 144 + kb * 32 + l4 * 8) = pk[kb];
        lds_fence();

        // ---- PV: A = V^T rows (d), B = P^T ----
        bf16x8 p0 = *(const bf16x8*)((const char*)&Psm[wv][0] + l15 * 144 + l4 * 16);
        bf16x8 p1 = *(const bf16x8*)((const char*)&Psm[wv][0] + l15 * 144 + 64 + l4 * 16);
#pragma unroll
        for (int db = 0; db < 4; ++db) {
            bf16x8 v0 = *(const bf16x8*)((const char*)Vsm + (db * 16 + l15) * 144 + l4 * 16);
            bf16x8 v1 = *(const bf16x8*)((const char*)Vsm + (db * 16 + l15) * 144 + 64 + l4 * 16);
            o[db] = MFMA16(v0, p0, o[db]);
            o[db] = MFMA16(v1, p1, o[db]);
        }
    }

    // ---- epilogue: normalize, transpose via LDS, coalesced f32 stores ----
    const float inv = 1.0f / l_run;
#pragma unroll
    for (int db = 0; db < 4; ++db)
#pragma unroll
        for (int r = 0; r < 4; ++r)
            osm[wv][l15 * 65 + db * 16 + l4 * 4 + r] = o[db][r] * inv;
    lds_fence();
    const size_t nbase = (size_t)qt * 64 + wv * 16;
#pragma unroll
    for (int qi = 0; qi < 16; ++qi)
        out[((size_t)b * 2048 + nbase + qi) * 1024 + h * 64 + l] = osm[wv][qi * 65 + l];
}

// ---------------------------------------------------------------------------
extern "C" void kernel_launch(void* const* d_in, const int* in_sizes, int n_in,
                              void* d_out, int out_size, void* d_ws, size_t ws_size,
                              hipStream_t stream) {
    const float* tokens = (const float*)d_in[0];
    // d_in[1] = sen   : DEAD (softmax shift invariance)
    const float* W1 = (const float*)d_in[2];
    // d_in[3] = W2    : DEAD
    const int* mask = (const int*)d_in[4];
    float* out = (float*)d_out;

    char* w = (char*)d_ws;
    __bf16* tokbf = (__bf16*)(w + 0);           // 16,777,216 B
    __bf16* w1t   = (__bf16*)(w + 16777216);    //  6,291,456 B
    __bf16* qarr  = (__bf16*)(w + 23068672);    // 16,777,216 B
    __bf16* karr  = (__bf16*)(w + 39845888);    // 16,777,216 B
    __bf16* vtar  = (__bf16*)(w + 56623104);    // 16,777,216 B
    float*  pend  = (float*)(w + 73400320);     //     32,768 B  (total 73.4 MB)

    k_cvt_tok<<<8192, 256, 0, stream>>>(tokens, tokbf);
    k_w1t<<<3072, 256, 0, stream>>>(W1, w1t);
    k_mask<<<32, 256, 0, stream>>>(mask, pend);
    k_gemm_qkv<<<1536, 256, 0, stream>>>(tokbf, w1t, qarr, karr, vtar);
    k_attn<<<2048, 256, 0, stream>>>(qarr, karr, vtar, pend, out);
}

// Round 3
// 322.148 us; speedup vs baseline: 1.0311x; 1.0311x over previous
//
#include <hip/hip_runtime.h>
#include <cstdint>

// ============================================================================
// Dual-source attention, MI355X. sen/W2 are dead (softmax shift invariance).
// Round-3 structure:
//  - Q pre-scaled by SCALE*log2(e) in GEMM epilogue -> scores in exp2 domain.
//  - Mask folded into V (zeroed rows) + flag row 64 of V^T; denominator
//    sum(flag*p) computed by an extra PV MFMA pair (row 64 of O^T).
//  - Defer-max (THR=8): skip o-rescale when tile max doesn't grow.
//  - GEMM staging via global_load_lds width=16, linear LDS.
// ============================================================================

typedef __bf16 bf16x8 __attribute__((ext_vector_type(8)));
typedef __bf16 bf16x4 __attribute__((ext_vector_type(4)));
typedef float  f32x4  __attribute__((ext_vector_type(4)));

#define MFMA16(a, b, c) __builtin_amdgcn_mfma_f32_16x16x32_bf16(a, b, c, 0, 0, 0)

__device__ __forceinline__ float exp2_raw(float x) {
    float r; asm("v_exp_f32 %0, %1" : "=v"(r) : "v"(x)); return r;
}
__device__ __forceinline__ void lds_fence() {
    asm volatile("s_waitcnt lgkmcnt(0)" ::: "memory");
    __builtin_amdgcn_sched_barrier(0);
}

static constexpr float QSCALE = 0.12751879523486166f;  // (2*64)^-0.5 * log2(e)

// ---------------------------------------------------------------------------
__global__ __launch_bounds__(256) void k_cvt_tok(const float* __restrict__ in,
                                                 __bf16* __restrict__ out) {
    int i = (blockIdx.x * 256 + threadIdx.x) * 4;
    float4 v = *(const float4*)&in[i];
    bf16x4 o = {(__bf16)v.x, (__bf16)v.y, (__bf16)v.z, (__bf16)v.w};
    *(bf16x4*)&out[i] = o;
}

// ---------------------------------------------------------------------------
__global__ __launch_bounds__(256) void k_w1t(const float* __restrict__ W1,
                                             __bf16* __restrict__ W1T) {
    __shared__ float t[32][33];
    int bx = blockIdx.x % 96, by = blockIdx.x / 96;
    int r0 = by * 32, c0 = bx * 32;
    int tr = threadIdx.x >> 3, tc = (threadIdx.x & 7) * 4;
    float4 v = *(const float4*)&W1[(size_t)(r0 + tr) * 3072 + c0 + tc];
    t[tr][tc + 0] = v.x; t[tr][tc + 1] = v.y; t[tr][tc + 2] = v.z; t[tr][tc + 3] = v.w;
    __syncthreads();
    bf16x4 o = {(__bf16)t[tc + 0][tr], (__bf16)t[tc + 1][tr],
                (__bf16)t[tc + 2][tr], (__bf16)t[tc + 3][tr]};
    *(bf16x4*)&W1T[(size_t)(c0 + tr) * 1024 + r0 + tc] = o;
}

// ---------------------------------------------------------------------------
// mask int32 [4][2048] -> bf16 flag (1.0 / 0.0)
__global__ __launch_bounds__(256) void k_mask(const int* __restrict__ m,
                                              __bf16* __restrict__ fl) {
    int i = blockIdx.x * 256 + threadIdx.x;
    fl[i] = (__bf16)(float)m[i];
}

// ---------------------------------------------------------------------------
// GEMM: C[8192][3072] = A @ W1, staging via global_load_lds w16, linear LDS.
// Epilogue: Q *= QSCALE; V *= flag (masked keys zeroed), stored transposed.
// ---------------------------------------------------------------------------
__global__ __launch_bounds__(256) void k_gemm_qkv(const __bf16* __restrict__ A,
                                                  const __bf16* __restrict__ BT,
                                                  const __bf16* __restrict__ FLAG,
                                                  __bf16* __restrict__ Q,
                                                  __bf16* __restrict__ K,
                                                  __bf16* __restrict__ VT) {
    __shared__ __align__(16) __bf16 Asm[128 * 32];  // linear [128][32], 64B rows
    __shared__ __align__(16) __bf16 Bsm[128 * 32];
    const int tid = threadIdx.x;
    const int tm = blockIdx.x / 24, tn = blockIdx.x % 24;
    const int m0 = tm * 128, n0 = tn * 128;
    const int l = tid & 63, wv = tid >> 6;
    const int l15 = l & 15, l4 = l >> 4;
    const int wr = wv >> 1, wc = wv & 1;

    // per-lane global byte offsets for global_load_lds (16B/lane, 16 rows/instr)
    const size_t aoff = (size_t)(m0 + wv * 32 + (l >> 2)) * 2048 + (l & 3) * 16;
    const size_t boff = (size_t)(n0 + wv * 32 + (l >> 2)) * 2048 + (l & 3) * 16;
    const char* Ab = (const char*)A;
    const char* Bb = (const char*)BT;
    char* asml = (char*)Asm + wv * 2048;
    char* bsml = (char*)Bsm + wv * 2048;

    f32x4 acc[4][4];
#pragma unroll
    for (int i = 0; i < 4; ++i)
#pragma unroll
        for (int j = 0; j < 4; ++j) acc[i][j] = (f32x4){0.f, 0.f, 0.f, 0.f};

    for (int kt = 0; kt < 32; ++kt) {
        __syncthreads();  // prev iter frag reads done
#pragma unroll
        for (int i = 0; i < 2; ++i) {
            __builtin_amdgcn_global_load_lds(
                (const __attribute__((address_space(1))) void*)(Ab + aoff + (size_t)i * 32768 + (size_t)kt * 64),
                (__attribute__((address_space(3))) void*)(asml + i * 1024), 16, 0, 0);
            __builtin_amdgcn_global_load_lds(
                (const __attribute__((address_space(1))) void*)(Bb + boff + (size_t)i * 32768 + (size_t)kt * 64),
                (__attribute__((address_space(3))) void*)(bsml + i * 1024), 16, 0, 0);
        }
        __syncthreads();  // drains vmcnt before frag reads

        bf16x8 af[4], bb[4];
#pragma unroll
        for (int mi = 0; mi < 4; ++mi)
            af[mi] = *(const bf16x8*)((const char*)Asm + (wr * 64 + mi * 16 + l15) * 64 + l4 * 16);
#pragma unroll
        for (int ni = 0; ni < 4; ++ni)
            bb[ni] = *(const bf16x8*)((const char*)Bsm + (wc * 64 + ni * 16 + l15) * 64 + l4 * 16);
#pragma unroll
        for (int mi = 0; mi < 4; ++mi)
#pragma unroll
            for (int ni = 0; ni < 4; ++ni)
                acc[mi][ni] = MFMA16(af[mi], bb[ni], acc[mi][ni]);
    }

    // Epilogue. D-frag: row = (l>>4)*4 + r, col = l&15.
#pragma unroll
    for (int mi = 0; mi < 4; ++mi) {
        const int rowb = m0 + wr * 64 + mi * 16 + l4 * 4;
        const int b = rowb >> 11, n = rowb & 2047;
#pragma unroll
        for (int ni = 0; ni < 4; ++ni) {
            const int col = n0 + wc * 64 + ni * 16 + l15;
            const int str = col >> 10, cc = col & 1023;
            const int h = cc >> 6, d = cc & 63;
            const int bh = b * 16 + h;
            if (str == 2) {
                const bf16x4 fl = *(const bf16x4*)&FLAG[b * 2048 + n];
                bf16x4 pv = {(__bf16)(acc[mi][ni][0] * (float)fl[0]),
                             (__bf16)(acc[mi][ni][1] * (float)fl[1]),
                             (__bf16)(acc[mi][ni][2] * (float)fl[2]),
                             (__bf16)(acc[mi][ni][3] * (float)fl[3])};
                *(bf16x4*)&VT[((size_t)bh * 64 + d) * 2048 + n] = pv;
            } else if (str == 0) {
#pragma unroll
                for (int r = 0; r < 4; ++r)
                    Q[((size_t)bh * 2048 + n + r) * 64 + d] = (__bf16)(acc[mi][ni][r] * QSCALE);
            } else {
#pragma unroll
                for (int r = 0; r < 4; ++r)
                    K[((size_t)bh * 2048 + n + r) * 64 + d] = (__bf16)acc[mi][ni][r];
            }
        }
    }
}

// ---------------------------------------------------------------------------
// Flash attention. 64 bh x 32 qtiles, 4 waves x 16 q-rows, 64-key tiles.
// Swapped QK^T (scores land per-lane, exp2 domain). Mask-free inner loop:
// denominator = row 64 of O^T via flag-row MFMA. Defer-max rescale.
// LDS 29.9KB -> 5 blocks/CU.
// ---------------------------------------------------------------------------
__global__ __launch_bounds__(256) void k_attn(const __bf16* __restrict__ Q,
                                              const __bf16* __restrict__ K,
                                              const __bf16* __restrict__ VT,
                                              const __bf16* __restrict__ FLAG,
                                              float* __restrict__ out) {
    __shared__ __align__(16) char smem[29952];
    __bf16* Ksm = (__bf16*)smem;            // [64][72] (144B rows)
    __bf16* Vsm = (__bf16*)(smem + 9216);   // [80][72]; row 64 = flag, 65..79 garbage (unused acc rows)
    char*   Psw = smem + 20736;             // 4 waves x [16][72]

    const int tid = threadIdx.x;
    const int bh = blockIdx.x >> 5, qt = blockIdx.x & 31;
    const int b = bh >> 4, h = bh & 15;
    const int wv = tid >> 6, l = tid & 63, l15 = l & 15, l4 = l >> 4;
    char* Pw = Psw + wv * 2304;

    // Q fragments in registers (already scaled by QSCALE)
    const size_t qrow = (size_t)bh * 2048 + qt * 64 + wv * 16 + l15;
    const bf16x8 q0 = *(const bf16x8*)&Q[qrow * 64 + l4 * 8];
    const bf16x8 q1 = *(const bf16x8*)&Q[qrow * 64 + 32 + l4 * 8];

    float m_run = -1e30f;
    f32x4 o[4], o4;
#pragma unroll
    for (int i = 0; i < 4; ++i) o[i] = (f32x4){0.f, 0.f, 0.f, 0.f};
    o4 = (f32x4){0.f, 0.f, 0.f, 0.f};

    const char* Kg = (const char*)K + (size_t)bh * 2048 * 128;
    const char* Vg = (const char*)VT + (size_t)bh * 64 * 4096;
    const char* Fg = (const char*)FLAG + (size_t)b * 4096;

    for (int t = 0; t < 32; ++t) {
        __syncthreads();  // prev tile compute done
#pragma unroll
        for (int i = 0; i < 2; ++i) {
            int c = tid * 2 + i;
            int row = c >> 3, qq = c & 7;
            *(uint4*)((char*)Ksm + row * 144 + qq * 16) =
                *(const uint4*)(Kg + (size_t)t * 8192 + c * 16);
            *(uint4*)((char*)Vsm + row * 144 + qq * 16) =
                *(const uint4*)(Vg + (size_t)row * 4096 + t * 128 + qq * 16);
        }
        if (tid < 8)  // flag row (V^T row 64) for this key tile
            *(uint4*)((char*)Vsm + 64 * 144 + tid * 16) = *(const uint4*)(Fg + t * 128 + tid * 16);
        __syncthreads();

        // ---- QK^T (swapped): scores ARE log2-domain (Q pre-scaled) ----
        f32x4 s[4];
#pragma unroll
        for (int kb = 0; kb < 4; ++kb) {
            bf16x8 kf0 = *(const bf16x8*)((const char*)Ksm + (kb * 16 + l15) * 144 + l4 * 16);
            bf16x8 kf1 = *(const bf16x8*)((const char*)Ksm + (kb * 16 + l15) * 144 + 64 + l4 * 16);
            s[kb] = (f32x4){0.f, 0.f, 0.f, 0.f};
            s[kb] = MFMA16(kf0, q0, s[kb]);
            s[kb] = MFMA16(kf1, q1, s[kb]);
        }

        // ---- row max (16 in-lane + 2 shfl) ----
        float mx = fmaxf(fmaxf(s[0][0], s[0][1]), fmaxf(s[0][2], s[0][3]));
#pragma unroll
        for (int kb = 1; kb < 4; ++kb)
            mx = fmaxf(mx, fmaxf(fmaxf(s[kb][0], s[kb][1]), fmaxf(s[kb][2], s[kb][3])));
        mx = fmaxf(mx, __shfl_xor(mx, 16, 64));
        mx = fmaxf(mx, __shfl_xor(mx, 32, 64));

        // ---- defer-max: rescale only when max grew past threshold ----
        if (!__all(mx <= m_run + 8.0f)) {
            const float m_new = fmaxf(m_run, mx);
            const float al = exp2_raw(m_run - m_new);
#pragma unroll
            for (int db = 0; db < 4; ++db) o[db] *= al;
            o4 *= al;
            m_run = m_new;
        }

        // ---- P = exp2(s - m), bf16 (bounded by 2^8) ----
        bf16x4 pk[4];
#pragma unroll
        for (int kb = 0; kb < 4; ++kb)
#pragma unroll
            for (int r = 0; r < 4; ++r)
                pk[kb][r] = (__bf16)exp2_raw(s[kb][r] - m_run);

        // ---- stage P^T (per-wave, wave-local fence) ----
#pragma unroll
        for (int kb = 0; kb < 4; ++kb)
            *(bf16x4*)(Pw + l15 * 144 + kb * 32 + l4 * 8) = pk[kb];
        lds_fence();

        bf16x8 p0 = *(const bf16x8*)(Pw + l15 * 144 + l4 * 16);
        bf16x8 p1 = *(const bf16x8*)(Pw + l15 * 144 + 64 + l4 * 16);
#pragma unroll
        for (int db = 0; db < 4; ++db) {
            bf16x8 v0 = *(const bf16x8*)((const char*)Vsm + (db * 16 + l15) * 144 + l4 * 16);
            bf16x8 v1 = *(const bf16x8*)((const char*)Vsm + (db * 16 + l15) * 144 + 64 + l4 * 16);
            o[db] = MFMA16(v0, p0, o[db]);
            o[db] = MFMA16(v1, p1, o[db]);
        }
        {   // denominator row: flag x P (only D-row 64 is consumed)
            bf16x8 f0 = *(const bf16x8*)((const char*)Vsm + (64 + l15) * 144 + l4 * 16);
            bf16x8 f1 = *(const bf16x8*)((const char*)Vsm + (64 + l15) * 144 + 64 + l4 * 16);
            o4 = MFMA16(f0, p0, o4);
            o4 = MFMA16(f1, p1, o4);
        }
    }

    // ---- epilogue: denom from lane l15 (D row 64, col = q), osm overlays K/V ----
    __syncthreads();  // all waves done with Ksm/Vsm before overlay
    const float denom = __shfl(o4[0], l15, 64);
    const float inv = 1.0f / denom;
    float* osm = (float*)smem + wv * 1040;  // 16*65 floats per wave
#pragma unroll
    for (int db = 0; db < 4; ++db)
#pragma unroll
        for (int r = 0; r < 4; ++r)
            osm[l15 * 65 + db * 16 + l4 * 4 + r] = o[db][r] * inv;
    lds_fence();
    const size_t nbase = (size_t)qt * 64 + wv * 16;
#pragma unroll
    for (int qi = 0; qi < 16; ++qi)
        out[((size_t)b * 2048 + nbase + qi) * 1024 + h * 64 + l] = osm[qi * 65 + l];
}

// ---------------------------------------------------------------------------
extern "C" void kernel_launch(void* const* d_in, const int* in_sizes, int n_in,
                              void* d_out, int out_size, void* d_ws, size_t ws_size,
                              hipStream_t stream) {
    const float* tokens = (const float*)d_in[0];
    // d_in[1] = sen : DEAD, d_in[3] = W2 : DEAD
    const float* W1 = (const float*)d_in[2];
    const int* mask = (const int*)d_in[4];
    float* out = (float*)d_out;

    char* w = (char*)d_ws;
    __bf16* tokbf = (__bf16*)(w + 0);           // 16,777,216 B
    __bf16* w1t   = (__bf16*)(w + 16777216);    //  6,291,456 B
    __bf16* qarr  = (__bf16*)(w + 23068672);    // 16,777,216 B
    __bf16* karr  = (__bf16*)(w + 39845888);    // 16,777,216 B
    __bf16* vtar  = (__bf16*)(w + 56623104);    // 16,777,216 B
    __bf16* flagb = (__bf16*)(w + 73400320);    //     16,384 B (total 73.42 MB)

    k_cvt_tok<<<8192, 256, 0, stream>>>(tokens, tokbf);
    k_w1t<<<3072, 256, 0, stream>>>(W1, w1t);
    k_mask<<<32, 256, 0, stream>>>(mask, flagb);
    k_gemm_qkv<<<1536, 256, 0, stream>>>(tokbf, w1t, flagb, qarr, karr, vtar);
    k_attn<<<2048, 256, 0, stream>>>(qarr, karr, vtar, flagb, out);
}

// Round 4
// 264.772 us; speedup vs baseline: 1.2546x; 1.2167x over previous
//
#include <hip/hip_runtime.h>
#include <cstdint>

// ============================================================================
// Dual-source attention, MI355X. sen/W2 dead (softmax shift invariance).
// Round-4: 32x32x16 MFMA attn, 64 q/wave, slot-permuted V so P-frags are pure
// in-register cvt_pk (no LDS P, no lane exchange), d-chunked conflict-free
// LDS tiles, prefetch-pipelined staging, flag-row MFMA denominator.
// ============================================================================

typedef __bf16 bf16x8 __attribute__((ext_vector_type(8)));
typedef __bf16 bf16x4 __attribute__((ext_vector_type(4)));
typedef float  f32x4  __attribute__((ext_vector_type(4)));
typedef float  f32x16 __attribute__((ext_vector_type(16)));
typedef unsigned int u32x4 __attribute__((ext_vector_type(4)));

#define MFMA16(a,b,c) __builtin_amdgcn_mfma_f32_16x16x32_bf16(a,b,c,0,0,0)
#define MFMA32(a,b,c) __builtin_amdgcn_mfma_f32_32x32x16_bf16(a,b,c,0,0,0)

static __device__ __forceinline__ float exp2_raw(float x) {
    float r; asm("v_exp_f32 %0, %1" : "=v"(r) : "v"(x)); return r;
}
static __device__ __forceinline__ uint32_t pkbf16(float a, float b) {
    uint32_t r; asm("v_cvt_pk_bf16_f32 %0, %1, %2" : "=v"(r) : "v"(a), "v"(b)); return r;
}
static __device__ __forceinline__ void lds_fence() {
    asm volatile("s_waitcnt lgkmcnt(0)" ::: "memory");
    __builtin_amdgcn_sched_barrier(0);
}
static __device__ __forceinline__ f32x16 zero16() {
    f32x16 z;
#pragma unroll
    for (int i = 0; i < 16; ++i) z[i] = 0.f;
    return z;
}
static __device__ __forceinline__ bf16x8 zero8() {
    return __builtin_bit_cast(bf16x8, (u32x4){0u, 0u, 0u, 0u});
}

#define GLLDS(src, dst)                                                        \
    __builtin_amdgcn_global_load_lds(                                          \
        (const __attribute__((address_space(1))) void*)(src),                  \
        (__attribute__((address_space(3))) void*)(dst), 16, 0, 0)

static constexpr float QSCALE = 0.12751879523486166f;  // (2*64)^-0.5 * log2(e)

// ---------------------------------------------------------------------------
__global__ __launch_bounds__(256) void k_cvt_tok(const float* __restrict__ in,
                                                 __bf16* __restrict__ out) {
    int i = (blockIdx.x * 256 + threadIdx.x) * 4;
    float4 v = *(const float4*)&in[i];
    bf16x4 o = {(__bf16)v.x, (__bf16)v.y, (__bf16)v.z, (__bf16)v.w};
    *(bf16x4*)&out[i] = o;
}

// ---------------------------------------------------------------------------
__global__ __launch_bounds__(256) void k_w1t(const float* __restrict__ W1,
                                             __bf16* __restrict__ W1T) {
    __shared__ float t[32][33];
    int bx = blockIdx.x % 96, by = blockIdx.x / 96;
    int r0 = by * 32, c0 = bx * 32;
    int tr = threadIdx.x >> 3, tc = (threadIdx.x & 7) * 4;
    float4 v = *(const float4*)&W1[(size_t)(r0 + tr) * 3072 + c0 + tc];
    t[tr][tc + 0] = v.x; t[tr][tc + 1] = v.y; t[tr][tc + 2] = v.z; t[tr][tc + 3] = v.w;
    __syncthreads();
    bf16x4 o = {(__bf16)t[tc + 0][tr], (__bf16)t[tc + 1][tr],
                (__bf16)t[tc + 2][tr], (__bf16)t[tc + 3][tr]};
    *(bf16x4*)&W1T[(size_t)(c0 + tr) * 1024 + r0 + tc] = o;
}

// ---------------------------------------------------------------------------
// mask -> flag bf16 (orig order, for V-zeroing) + slot-permuted flagp (for the
// denominator MFMA A-row).  slot = {k[4:3], k[2], k[5], k[1:0]}.
__global__ __launch_bounds__(256) void k_mask(const int* __restrict__ m,
                                              __bf16* __restrict__ fl,
                                              __bf16* __restrict__ flp) {
    int i = blockIdx.x * 256 + threadIdx.x;
    fl[i] = (__bf16)(float)m[i];
    int s6 = i & 63;
    int kp = ((s6 >> 2) & 1) * 32 + ((s6 >> 4) & 3) * 8 + ((s6 >> 3) & 1) * 4 + (s6 & 3);
    flp[i] = (__bf16)(float)m[(i & ~63) | kp];
}

// ---------------------------------------------------------------------------
// GEMM C[8192][3072] = A @ W1 (BT pre-transposed). 128x128 tile, BK=32,
// double-buffered global_load_lds staging, one barrier per K-step.
// Epilogue: Q *= QSCALE; K plain; V *= flag, transposed AND slot-permuted.
// ---------------------------------------------------------------------------
__global__ __launch_bounds__(256) void k_gemm_qkv(const __bf16* __restrict__ A,
                                                  const __bf16* __restrict__ BT,
                                                  const __bf16* __restrict__ FLAG,
                                                  __bf16* __restrict__ Q,
                                                  __bf16* __restrict__ K,
                                                  __bf16* __restrict__ VT) {
    __shared__ __align__(16) char gsm[32768];  // 2 x (A 8KB + B 8KB)
    const int tid = threadIdx.x;
    const int bid = blockIdx.x;
    const int sw = (bid & 7) * 192 + (bid >> 3);  // XCD-chunked (1536 % 8 == 0)
    const int tm = sw / 24, tn = sw % 24;
    const int m0 = tm * 128, n0 = tn * 128;
    const int l = tid & 63, wv = tid >> 6;
    const int l15 = l & 15, l4 = l >> 4;
    const int wr = wv >> 1, wc = wv & 1;

    const char* Ab = (const char*)A;
    const char* Bb = (const char*)BT;
    const size_t aoff = (size_t)(m0 + wv * 32 + (l >> 2)) * 2048 + (l & 3) * 16;
    const size_t boff = (size_t)(n0 + wv * 32 + (l >> 2)) * 2048 + (l & 3) * 16;

    f32x4 acc[4][4];
#pragma unroll
    for (int i = 0; i < 4; ++i)
#pragma unroll
        for (int j = 0; j < 4; ++j) acc[i][j] = (f32x4){0.f, 0.f, 0.f, 0.f};

    auto STAGE = [&](int nb, int kt) {
        char* ab = gsm + nb * 16384 + wv * 2048;
        char* bb = ab + 8192;
#pragma unroll
        for (int i = 0; i < 2; ++i) {
            GLLDS(Ab + aoff + (size_t)i * 32768 + (size_t)kt * 64, ab + i * 1024);
            GLLDS(Bb + boff + (size_t)i * 32768 + (size_t)kt * 64, bb + i * 1024);
        }
    };
    STAGE(0, 0);

    for (int kt = 0; kt < 32; ++kt) {
        const int cur = kt & 1;
        __syncthreads();                    // buf[cur] staged; prev reads done
        if (kt < 31) STAGE(cur ^ 1, kt + 1);  // hidden under this tile's MFMA
        const char* As = gsm + cur * 16384;
        const char* Bs = As + 8192;

        bf16x8 af[4], bb[4];
#pragma unroll
        for (int mi = 0; mi < 4; ++mi)
            af[mi] = *(const bf16x8*)(As + (wr * 64 + mi * 16 + l15) * 64 + l4 * 16);
#pragma unroll
        for (int ni = 0; ni < 4; ++ni)
            bb[ni] = *(const bf16x8*)(Bs + (wc * 64 + ni * 16 + l15) * 64 + l4 * 16);
#pragma unroll
        for (int mi = 0; mi < 4; ++mi)
#pragma unroll
            for (int ni = 0; ni < 4; ++ni)
                acc[mi][ni] = MFMA16(af[mi], bb[ni], acc[mi][ni]);
    }

    // Epilogue. D-frag: row = (l>>4)*4 + r, col = l&15.
#pragma unroll
    for (int mi = 0; mi < 4; ++mi) {
        const int rowb = m0 + wr * 64 + mi * 16 + l4 * 4;
        const int b = rowb >> 11, n = rowb & 2047;
#pragma unroll
        for (int ni = 0; ni < 4; ++ni) {
            const int col = n0 + wc * 64 + ni * 16 + l15;
            const int str = col >> 10, cc = col & 1023;
            const int h = cc >> 6, d = cc & 63;
            const int bh = b * 16 + h;
            if (str == 2) {
                const bf16x4 fv = *(const bf16x4*)&FLAG[b * 2048 + n];
                bf16x4 pv = {(__bf16)(acc[mi][ni][0] * (float)fv[0]),
                             (__bf16)(acc[mi][ni][1] * (float)fv[1]),
                             (__bf16)(acc[mi][ni][2] * (float)fv[2]),
                             (__bf16)(acc[mi][ni][3] * (float)fv[3])};
                const int k6 = n & 63;  // low 2 bits are 0; r appends slot[1:0]
                const int nsl = (n & ~63) | (((k6 >> 3) & 3) << 4) |
                                (((k6 >> 2) & 1) << 3) | ((k6 >> 5) << 2);
                *(bf16x4*)&VT[((size_t)bh * 64 + d) * 2048 + nsl] = pv;
            } else if (str == 0) {
#pragma unroll
                for (int r = 0; r < 4; ++r)
                    Q[((size_t)bh * 2048 + n + r) * 64 + d] = (__bf16)(acc[mi][ni][r] * QSCALE);
            } else {
#pragma unroll
                for (int r = 0; r < 4; ++r)
                    K[((size_t)bh * 2048 + n + r) * 64 + d] = (__bf16)acc[mi][ni][r];
            }
        }
    }
}

// ---------------------------------------------------------------------------
// Flash attention, 32x32x16 MFMA. 64 bh x 8 qtiles (XCD-chunked), 4 waves x
// 64 q-rows, 64-key tiles. LDS: d-chunked [4][64][32B] K and V tiles
// (conflict-free ds_read_b128), double-buffered, 1 barrier/tile.
// S^T = K·Q^T per 32-q coltile; P-frags built in-register via v_cvt_pk
// (slot-permuted V makes the layouts line up). Denominator via flag-row MFMA.
// ---------------------------------------------------------------------------
__global__ __launch_bounds__(256, 2) void k_attn(const __bf16* __restrict__ Q,
                                                 const __bf16* __restrict__ K,
                                                 const __bf16* __restrict__ VT,
                                                 const __bf16* __restrict__ FLAGP,
                                                 float* __restrict__ out) {
    __shared__ __align__(16) char smem[33280];  // 2x16KB staging; epilogue overlay
    const int tid = threadIdx.x;
    const int bid = blockIdx.x;
    const int swz = (bid & 7) * 64 + (bid >> 3);  // XCD-chunked (512 = 8*64)
    const int bh = swz >> 3, qt = swz & 7;
    const int b = bh >> 4, h = bh & 15;
    const int wv = tid >> 6, l = tid & 63, l31 = l & 31, hi = l >> 5;

    const char* Kg = (const char*)K + (size_t)bh * 2048 * 128;
    const char* Vg = (const char*)VT + (size_t)bh * 64 * 4096;
    const __bf16* Fg = FLAGP + b * 2048;

    // Q fragments (pre-scaled by QSCALE*log2e): B-operand, col = q
    const __bf16* qp = Q + ((size_t)bh * 2048 + qt * 256 + wv * 64 + l31) * 64;
    bf16x8 qf0[4], qf1[4];
#pragma unroll
    for (int m = 0; m < 4; ++m) {
        qf0[m] = *(const bf16x8*)(qp + m * 16 + hi * 8);
        qf1[m] = *(const bf16x8*)(qp + 32 * 64 + m * 16 + hi * 8);
    }

    f32x16 o00 = zero16(), o01 = zero16(), o10 = zero16(), o11 = zero16();
    f32x16 fa0 = zero16(), fa1 = zero16();
    float mr0 = -1e30f, mr1 = -1e30f;

    auto STAGE = [&](int nb, int t) {
        char* base = smem + nb * 16384;
#pragma unroll
        for (int i = 0; i < 2; ++i) {
            const int blk = wv + i * 4;            // 0..7 (1KB chunks)
            const int mc = blk >> 1, rb = blk & 1;
            const int row = rb * 32 + (l >> 1);    // key row / d row
            GLLDS(Kg + (size_t)(t * 64 + row) * 128 + mc * 32 + (l & 1) * 16,
                  base + blk * 1024);
            GLLDS(Vg + (size_t)row * 4096 + t * 128 + mc * 32 + (l & 1) * 16,
                  base + 8192 + blk * 1024);
        }
    };
    STAGE(0, 0);

    for (int t = 0; t < 32; ++t) {
        const int cur = t & 1;
        __syncthreads();                      // buf[cur] ready; prev reads done
        if (t < 31) STAGE(cur ^ 1, t + 1);    // prefetch hides under compute
        const char* Ks = smem + cur * 16384;
        const char* Vs = Ks + 8192;

        // K fragments: A-operand, row = key (d-chunked layout, conflict-free)
        bf16x8 kf0[4], kf1[4];
#pragma unroll
        for (int m = 0; m < 4; ++m) {
            kf0[m] = *(const bf16x8*)(Ks + m * 2048 + l31 * 32 + hi * 16);
            kf1[m] = *(const bf16x8*)(Ks + m * 2048 + (32 + l31) * 32 + hi * 16);
        }

        // ---- coltile 0: S^T = K·Q^T, softmax, pack ----
        f32x16 s0 = zero16(), s1 = zero16();
#pragma unroll
        for (int m = 0; m < 4; ++m) s0 = MFMA32(kf0[m], qf0[m], s0);
#pragma unroll
        for (int m = 0; m < 4; ++m) s1 = MFMA32(kf1[m], qf0[m], s1);
        {
            float mx = fmaxf(s0[0], s1[0]);
#pragma unroll
            for (int i = 1; i < 16; ++i) mx = fmaxf(mx, fmaxf(s0[i], s1[i]));
            mx = fmaxf(mx, __shfl_xor(mx, 32, 64));
            if (!__all(mx <= mr0 + 8.0f)) {     // defer-max (T13)
                float mn = fmaxf(mr0, mx);
                float al = exp2_raw(mr0 - mn);
                o00 *= al; o01 *= al; fa0 *= al; mr0 = mn;
            }
        }
        u32x4 pk0[4];
#pragma unroll
        for (int m = 0; m < 4; ++m) {
            pk0[m].x = pkbf16(exp2_raw(s0[4 * m] - mr0), exp2_raw(s0[4 * m + 1] - mr0));
            pk0[m].y = pkbf16(exp2_raw(s0[4 * m + 2] - mr0), exp2_raw(s0[4 * m + 3] - mr0));
            pk0[m].z = pkbf16(exp2_raw(s1[4 * m] - mr0), exp2_raw(s1[4 * m + 1] - mr0));
            pk0[m].w = pkbf16(exp2_raw(s1[4 * m + 2] - mr0), exp2_raw(s1[4 * m + 3] - mr0));
        }

        // flag A-row (only lanes with l31==0 carry data; rest zero)
        bf16x8 ff[4];
#pragma unroll
        for (int m = 0; m < 4; ++m) ff[m] = zero8();
        if (l31 == 0) {
#pragma unroll
            for (int m = 0; m < 4; ++m)
                ff[m] = *(const bf16x8*)(Fg + t * 64 + m * 16 + hi * 8);
        }

        // ---- coltile 1 ----
        s0 = zero16(); s1 = zero16();
#pragma unroll
        for (int m = 0; m < 4; ++m) s0 = MFMA32(kf0[m], qf1[m], s0);
#pragma unroll
        for (int m = 0; m < 4; ++m) s1 = MFMA32(kf1[m], qf1[m], s1);
        {
            float mx = fmaxf(s0[0], s1[0]);
#pragma unroll
            for (int i = 1; i < 16; ++i) mx = fmaxf(mx, fmaxf(s0[i], s1[i]));
            mx = fmaxf(mx, __shfl_xor(mx, 32, 64));
            if (!__all(mx <= mr1 + 8.0f)) {
                float mn = fmaxf(mr1, mx);
                float al = exp2_raw(mr1 - mn);
                o10 *= al; o11 *= al; fa1 *= al; mr1 = mn;
            }
        }
        u32x4 pk1[4];
#pragma unroll
        for (int m = 0; m < 4; ++m) {
            pk1[m].x = pkbf16(exp2_raw(s0[4 * m] - mr1), exp2_raw(s0[4 * m + 1] - mr1));
            pk1[m].y = pkbf16(exp2_raw(s0[4 * m + 2] - mr1), exp2_raw(s0[4 * m + 3] - mr1));
            pk1[m].z = pkbf16(exp2_raw(s1[4 * m] - mr1), exp2_raw(s1[4 * m + 1] - mr1));
            pk1[m].w = pkbf16(exp2_raw(s1[4 * m + 2] - mr1), exp2_raw(s1[4 * m + 3] - mr1));
        }

        // ---- PV + denominator ----
#pragma unroll
        for (int m = 0; m < 4; ++m) {
            bf16x8 vf0 = *(const bf16x8*)(Vs + m * 2048 + l31 * 32 + hi * 16);
            bf16x8 vf1 = *(const bf16x8*)(Vs + m * 2048 + (32 + l31) * 32 + hi * 16);
            bf16x8 p0 = __builtin_bit_cast(bf16x8, pk0[m]);
            bf16x8 p1 = __builtin_bit_cast(bf16x8, pk1[m]);
            o00 = MFMA32(vf0, p0, o00);
            o01 = MFMA32(vf1, p0, o01);
            o10 = MFMA32(vf0, p1, o10);
            o11 = MFMA32(vf1, p1, o11);
            fa0 = MFMA32(ff[m], p0, fa0);
            fa1 = MFMA32(ff[m], p1, fa1);
        }
    }

    // ---- epilogue: denom = flag-acc row 0 (hi=0 lanes), transpose via LDS ----
    __syncthreads();
    float* osm = (float*)smem + wv * 2080;  // 32 x 65 f32 per wave
    const size_t obase = ((size_t)b * 2048 + qt * 256 + wv * 64) * 1024 + h * 64 + l;
    {
        const float inv = 1.0f / __shfl(fa0[0], l31, 64);
#pragma unroll
        for (int r = 0; r < 16; ++r) {
            const int d = (r & 3) + 8 * (r >> 2) + 4 * hi;
            osm[l31 * 65 + d] = o00[r] * inv;
            osm[l31 * 65 + d + 32] = o01[r] * inv;
        }
        lds_fence();
#pragma unroll
        for (int qi = 0; qi < 32; ++qi)
            out[obase + (size_t)qi * 1024] = osm[qi * 65 + l];
        lds_fence();
    }
    {
        const float inv = 1.0f / __shfl(fa1[0], l31, 64);
#pragma unroll
        for (int r = 0; r < 16; ++r) {
            const int d = (r & 3) + 8 * (r >> 2) + 4 * hi;
            osm[l31 * 65 + d] = o10[r] * inv;
            osm[l31 * 65 + d + 32] = o11[r] * inv;
        }
        lds_fence();
#pragma unroll
        for (int qi = 0; qi < 32; ++qi)
            out[obase + (size_t)(32 + qi) * 1024] = osm[qi * 65 + l];
    }
}

// ---------------------------------------------------------------------------
extern "C" void kernel_launch(void* const* d_in, const int* in_sizes, int n_in,
                              void* d_out, int out_size, void* d_ws, size_t ws_size,
                              hipStream_t stream) {
    const float* tokens = (const float*)d_in[0];
    // d_in[1] = sen : DEAD, d_in[3] = W2 : DEAD
    const float* W1 = (const float*)d_in[2];
    const int* mask = (const int*)d_in[4];
    float* out = (float*)d_out;

    char* w = (char*)d_ws;
    __bf16* tokbf = (__bf16*)(w + 0);           // 16,777,216 B
    __bf16* w1t   = (__bf16*)(w + 16777216);    //  6,291,456 B
    __bf16* qarr  = (__bf16*)(w + 23068672);    // 16,777,216 B
    __bf16* karr  = (__bf16*)(w + 39845888);    // 16,777,216 B
    __bf16* vtar  = (__bf16*)(w + 56623104);    // 16,777,216 B (slot-permuted)
    __bf16* flagb = (__bf16*)(w + 73400320);    //     16,384 B (orig order)
    __bf16* flagp = (__bf16*)(w + 73416704);    //     16,384 B (slot-permuted)

    k_cvt_tok<<<8192, 256, 0, stream>>>(tokens, tokbf);
    k_w1t<<<3072, 256, 0, stream>>>(W1, w1t);
    k_mask<<<32, 256, 0, stream>>>(mask, flagb, flagp);
    k_gemm_qkv<<<1536, 256, 0, stream>>>(tokbf, w1t, flagb, qarr, karr, vtar);
    k_attn<<<512, 256, 0, stream>>>(qarr, karr, vtar, flagp, out);
}